// Round 4
// baseline (76.586 us; speedup 1.0000x reference)
//
#include <hip/hip_runtime.h>
#include <stdint.h>

#define B_  16
#define H_  512
#define W_  512
#define HW_ (H_*W_)
#define N_  (B_*HW_)

#define TX 64
#define TY 16

// LDS plane geometries (all scalar-addressed stencils, round-2 style)
#define AY 26
#define AX 80        // gray: rows ty0-5.., cols tx0-8.. (20 quads, 16B aligned)
#define TWY 26
#define TWX 70       // t (h-blur): cols tx0-3..
#define BLY 22
#define BLX 70       // blur: rows ty0-3..
#define MGY 20
#define MGX 68       // mag/dir: rows ty0-2.., cols tx0-2..
#define EY 18
#define EX 66        // e-class: rows ty0-1.., cols tx0-1..

#define G0 0.054488685f
#define G1 0.244201342f
#define G2 0.402619947f

// nibble LUTs: (dy+1), (dx+1) for direction p = 0..7 (E,NE,N,NW,W,SW,S,SE)
#define DYP 0x22210001u
#define DXP 0x21000122u

__device__ __forceinline__ int reflect512(int i) {
    i = i < 0 ? -i : i;
    return i > 511 ? 1022 - i : i;
}
__device__ __forceinline__ int clamp511(int v) {
    return v < 0 ? 0 : (v > 511 ? 511 : v);
}

__global__ __launch_bounds__(256)
void k_canny(const float* __restrict__ pred, const float* __restrict__ sketch,
             const float* __restrict__ matte, float* __restrict__ out) {
    __shared__ __align__(16) union { float g[AY][AX]; int e[EY][EX]; } uA;
    __shared__ __align__(16) union { float t[TWY][TWX]; float mag[MGY][MGX]; } uT;
    __shared__ __align__(16) float sBlur[BLY][BLX];
    __shared__ uint8_t sDir[MGY][MGX];
    __shared__ float wsum[4];

    const int tid = threadIdx.x;
    const int tx0 = blockIdx.x * TX;
    const int ty0 = blockIdx.y * TY;
    const int b   = blockIdx.z;

    const float* pb = pred   + (size_t)b * 3 * HW_;
    const float* mb = matte  + (size_t)b * HW_;
    const float* sb = sketch + (size_t)b * HW_;

    // ---- A: gray = mean3(pred)*matte, reflect-staged, [26][80], float4 fast path ----
    const bool xfast = (tx0 >= 8) && (tx0 <= 440);   // all 80 cols in-range, no x-reflect
    for (int u = tid; u < AY*20; u += 256) {
        int r = u / 20, q = u - r*20;
        int ys = reflect512(ty0 - 5 + r);
        int gx = tx0 - 8 + q*4;
        float4 res;
        if (xfast) {
            const float* prow = pb + ys*W_ + gx;
            float4 p0 = *(const float4*)(prow);
            float4 p1 = *(const float4*)(prow + HW_);
            float4 p2 = *(const float4*)(prow + 2*HW_);
            float4 m4 = *(const float4*)(mb + ys*W_ + gx);
            res.x = (p0.x+p1.x+p2.x)*m4.x*(1.f/3.f);
            res.y = (p0.y+p1.y+p2.y)*m4.y*(1.f/3.f);
            res.z = (p0.z+p1.z+p2.z)*m4.z*(1.f/3.f);
            res.w = (p0.w+p1.w+p2.w)*m4.w*(1.f/3.f);
        } else {
            float tmp[4];
            #pragma unroll
            for (int e = 0; e < 4; ++e) {
                int xs = reflect512(gx + e);
                int o  = ys*W_ + xs;
                tmp[e] = (pb[o] + pb[o+HW_] + pb[o+2*HW_]) * mb[o] * (1.f/3.f);
            }
            res.x = tmp[0]; res.y = tmp[1]; res.z = tmp[2]; res.w = tmp[3];
        }
        *(float4*)&uA.g[r][q*4] = res;
    }
    __syncthreads();

    // ---- B1: horizontal gaussian -> t [26][70], scalar LDS stencil ----
    for (int u = tid; u < TWY*TWX; u += 256) {
        int ly = u / TWX, lx = u - ly*TWX;
        int xc = clamp511(tx0 - 3 + lx) - (tx0 - 8);   // [5,74]
        float a = G0*uA.g[ly][xc-2] + G1*uA.g[ly][xc-1] + G2*uA.g[ly][xc]
                + G1*uA.g[ly][xc+1] + G0*uA.g[ly][xc+2];
        uT.t[ly][lx] = a;
    }
    __syncthreads();

    // ---- B2: vertical gaussian -> blur [22][70], scalar LDS stencil ----
    for (int u = tid; u < BLY*BLX; u += 256) {
        int ly = u / BLX, lx = u - ly*BLX;
        int yc = clamp511(ty0 - 3 + ly) - (ty0 - 5);   // [2,23]
        float a = G0*uT.t[yc-2][lx] + G1*uT.t[yc-1][lx] + G2*uT.t[yc][lx]
                + G1*uT.t[yc+1][lx] + G0*uT.t[yc+2][lx];
        sBlur[ly][lx] = a;
    }
    __syncthreads();

    // ---- C: sobel -> mag [20][68] (overwrites t) + dir, scalar ----
    for (int u = tid; u < MGY*MGX; u += 256) {
        int r = u / MGX, c = u - r*MGX;
        int y = ty0 - 2 + r, x = tx0 - 2 + c;
        float m = 0.f; int k = 0;
        if (y >= 0 && y < H_ && x >= 0 && x < W_) {
            int r0 = clamp511(y-1) - (ty0-3);
            int r1 = y - (ty0-3);
            int r2 = clamp511(y+1) - (ty0-3);
            int cm = clamp511(x-1) - (tx0-3);
            int cc = x - (tx0-3);
            int cp = clamp511(x+1) - (tx0-3);
            float a00 = sBlur[r0][cm], a01 = sBlur[r0][cc], a02 = sBlur[r0][cp];
            float a10 = sBlur[r1][cm],                      a12 = sBlur[r1][cp];
            float a20 = sBlur[r2][cm], a21 = sBlur[r2][cc], a22 = sBlur[r2][cp];
            float gxv = ((a02 + 2.f*a12 + a22) - (a00 + 2.f*a10 + a20)) * 0.125f;
            float gyv = ((a20 + 2.f*a21 + a22) - (a00 + 2.f*a01 + a02)) * 0.125f;
            m = sqrtf(gxv*gxv + gyv*gyv + 1e-6f);
            float agx = fabsf(gxv), agy = fabsf(gyv);
            if      (agy <= 0.41421356f * agx) k = (gxv >= 0.f) ? 0 : 4;
            else if (agy >= 2.41421356f * agx) k = (gyv >  0.f) ? 2 : 6;
            else k = (gyv > 0.f) ? ((gxv > 0.f) ? 1 : 3) : ((gxv > 0.f) ? 7 : 5);
        }
        uT.mag[r][c] = m;
        sDir[r][c] = (uint8_t)k;
    }
    __syncthreads();

    // ---- D: NMS + double threshold -> class [18][66] (overwrites gray) ----
    for (int u = tid; u < EY*EX; u += 256) {
        int r = u / EX, c = u - r*EX;
        float m = uT.mag[r+1][c+1];
        int p  = sDir[r+1][c+1];
        int qd = (p + 4) & 7;
        int dy1 = (int)((DYP >> (p*4))  & 7u) - 1;
        int dx1 = (int)((DXP >> (p*4))  & 7u) - 1;
        int dy2 = (int)((DYP >> (qd*4)) & 7u) - 1;
        int dx2 = (int)((DXP >> (qd*4)) & 7u) - 1;
        float n1 = uT.mag[r+1+dy1][c+1+dx1];
        float n2 = uT.mag[r+1+dy2][c+1+dx2];
        float mm = (fminf(m - n1, m - n2) > 0.f) ? m : 0.f;
        uA.e[r][c] = (mm > 0.1f) + (mm > 0.2f);
    }
    __syncthreads();

    // ---- E: guarded 1-sweep hysteresis + MSE ----
    {
        int r16 = tid >> 4, q16 = tid & 15;
        int gy = ty0 + r16, gx = tx0 + q16*4;
        int er = r16 + 1;            // row gy in e coords
        int ec = q16*4 + 1;          // col gx in e coords
        int cls[4];
        #pragma unroll
        for (int j = 0; j < 4; ++j) cls[j] = uA.e[er][ec+j];
        if (cls[0] == 1 || cls[1] == 1 || cls[2] == 1 || cls[3] == 1) {
            #pragma unroll
            for (int j = 0; j < 4; ++j) {
                if (cls[j] == 1) {
                    int cc = ec + j;
                    bool pr = (uA.e[er-1][cc-1] == 2) | (uA.e[er-1][cc] == 2) | (uA.e[er-1][cc+1] == 2)
                            | (uA.e[er  ][cc-1] == 2) |                         (uA.e[er  ][cc+1] == 2)
                            | (uA.e[er+1][cc-1] == 2) | (uA.e[er+1][cc] == 2) | (uA.e[er+1][cc+1] == 2);
                    if (pr) cls[j] = 2;
                }
            }
        }
        float4 s4 = *(const float4*)(sb + gy*W_ + gx);
        float4 m4 = *(const float4*)(mb + gy*W_ + gx);
        float lacc = 0.f, tt, d;
        tt = fminf(fmaxf(s4.x*m4.x, 0.f), 1.f); d = 0.5f*(float)cls[0] - tt; lacc += d*d;
        tt = fminf(fmaxf(s4.y*m4.y, 0.f), 1.f); d = 0.5f*(float)cls[1] - tt; lacc += d*d;
        tt = fminf(fmaxf(s4.z*m4.z, 0.f), 1.f); d = 0.5f*(float)cls[2] - tt; lacc += d*d;
        tt = fminf(fmaxf(s4.w*m4.w, 0.f), 1.f); d = 0.5f*(float)cls[3] - tt; lacc += d*d;

        #pragma unroll
        for (int off = 32; off > 0; off >>= 1)
            lacc += __shfl_down(lacc, off, 64);
        if ((tid & 63) == 0) wsum[tid >> 6] = lacc;
    }
    __syncthreads();
    if (tid == 0)
        atomicAdd(out, (wsum[0] + wsum[1] + wsum[2] + wsum[3]) * (1.0f / (float)N_));
}

extern "C" void kernel_launch(void* const* d_in, const int* in_sizes, int n_in,
                              void* d_out, int out_size, void* d_ws, size_t ws_size,
                              hipStream_t stream) {
    const float* pred   = (const float*)d_in[0];
    const float* sketch = (const float*)d_in[1];
    const float* matte  = (const float*)d_in[2];
    float* out = (float*)d_out;

    hipMemsetAsync(d_out, 0, sizeof(float), stream);
    dim3 blk(256);
    dim3 grd(W_/TX, H_/TY, B_);   // (8, 32, 16)
    k_canny<<<grd, blk, 0, stream>>>(pred, sketch, matte, out);
}

// Round 5
// 50.022 us; speedup vs baseline: 1.5310x; 1.5310x over previous
//
#include <hip/hip_runtime.h>
#include <stdint.h>

#define B_  16
#define H_  512
#define W_  512
#define HW_ (H_*W_)
#define N_  (B_*HW_)

#define TX 64
#define TY 32
#define NBLK (8*16*16)   // grid blocks = (512/64)*(512/32)*16 = 2048

// LDS plane geometries (scalar-addressed stencils)
#define AY 42
#define AX 80        // gray: rows ty0-5.., cols tx0-8..
#define TWY 42
#define TWX 70       // t (h-blur): cols tx0-3..
#define BLY 38
#define BLX 70       // blur: rows ty0-3..
#define MGY 36
#define MGX 68       // mag/dir: rows ty0-2.., cols tx0-2..
#define EY 34
#define EX 66        // e-class: rows ty0-1.., cols tx0-1..

#define G0 0.054488685f
#define G1 0.244201342f
#define G2 0.402619947f

// nibble LUTs: (dy+1), (dx+1) for direction p = 0..7 (E,NE,N,NW,W,SW,S,SE)
#define DYP 0x22210001u
#define DXP 0x21000122u

__device__ __forceinline__ int reflect512(int i) {
    i = i < 0 ? -i : i;
    return i > 511 ? 1022 - i : i;
}
__device__ __forceinline__ int clamp511(int v) {
    return v < 0 ? 0 : (v > 511 ? 511 : v);
}

__global__ __launch_bounds__(256)
void k_canny(const float* __restrict__ pred, const float* __restrict__ sketch,
             const float* __restrict__ matte, float* __restrict__ partials) {
    __shared__ __align__(16) union { float g[AY][AX]; int e[EY][EX]; } uA;
    __shared__ __align__(16) union { float t[TWY][TWX]; float mag[MGY][MGX]; } uT;
    __shared__ __align__(16) float sBlur[BLY][BLX];
    __shared__ uint8_t sDir[MGY][MGX];
    __shared__ float wsum[4];

    const int tid = threadIdx.x;
    const int tx0 = blockIdx.x * TX;
    const int ty0 = blockIdx.y * TY;
    const int b   = blockIdx.z;

    const float* pb = pred   + (size_t)b * 3 * HW_;
    const float* mb = matte  + (size_t)b * HW_;
    const float* sb = sketch + (size_t)b * HW_;

    // ---- A: gray = mean3(pred)*matte, reflect-staged, [42][80], float4 fast path ----
    const bool xfast = (tx0 >= 8) && (tx0 + 71 < W_);
    for (int u = tid; u < AY*20; u += 256) {
        int r = u / 20, q = u - r*20;
        int ys = reflect512(ty0 - 5 + r);
        int gx = tx0 - 8 + q*4;
        float4 res;
        if (xfast) {
            const float* prow = pb + ys*W_ + gx;
            float4 p0 = *(const float4*)(prow);
            float4 p1 = *(const float4*)(prow + HW_);
            float4 p2 = *(const float4*)(prow + 2*HW_);
            float4 m4 = *(const float4*)(mb + ys*W_ + gx);
            res.x = (p0.x+p1.x+p2.x)*m4.x*(1.f/3.f);
            res.y = (p0.y+p1.y+p2.y)*m4.y*(1.f/3.f);
            res.z = (p0.z+p1.z+p2.z)*m4.z*(1.f/3.f);
            res.w = (p0.w+p1.w+p2.w)*m4.w*(1.f/3.f);
        } else {
            float tmp[4];
            #pragma unroll
            for (int e = 0; e < 4; ++e) {
                int xs = reflect512(gx + e);
                int o  = ys*W_ + xs;
                tmp[e] = (pb[o] + pb[o+HW_] + pb[o+2*HW_]) * mb[o] * (1.f/3.f);
            }
            res.x = tmp[0]; res.y = tmp[1]; res.z = tmp[2]; res.w = tmp[3];
        }
        *(float4*)&uA.g[r][q*4] = res;
    }
    __syncthreads();

    // ---- B1: horizontal gaussian -> t [42][70], scalar LDS stencil ----
    for (int u = tid; u < TWY*TWX; u += 256) {
        int ly = u / TWX, lx = u - ly*TWX;
        int xc = clamp511(tx0 - 3 + lx) - (tx0 - 8);   // [5,74]
        float a = G0*uA.g[ly][xc-2] + G1*uA.g[ly][xc-1] + G2*uA.g[ly][xc]
                + G1*uA.g[ly][xc+1] + G0*uA.g[ly][xc+2];
        uT.t[ly][lx] = a;
    }
    __syncthreads();

    // ---- B2: vertical gaussian -> blur [38][70], scalar LDS stencil ----
    for (int u = tid; u < BLY*BLX; u += 256) {
        int ly = u / BLX, lx = u - ly*BLX;
        int yc = clamp511(ty0 - 3 + ly) - (ty0 - 5);   // [2,39]
        float a = G0*uT.t[yc-2][lx] + G1*uT.t[yc-1][lx] + G2*uT.t[yc][lx]
                + G1*uT.t[yc+1][lx] + G0*uT.t[yc+2][lx];
        sBlur[ly][lx] = a;
    }
    __syncthreads();

    // ---- C: sobel -> mag [36][68] (overwrites t) + dir, scalar ----
    for (int u = tid; u < MGY*MGX; u += 256) {
        int r = u / MGX, c = u - r*MGX;
        int y = ty0 - 2 + r, x = tx0 - 2 + c;
        float m = 0.f; int k = 0;
        if (y >= 0 && y < H_ && x >= 0 && x < W_) {
            int r0 = clamp511(y-1) - (ty0-3);
            int r1 = y - (ty0-3);
            int r2 = clamp511(y+1) - (ty0-3);
            int cm = clamp511(x-1) - (tx0-3);
            int cc = x - (tx0-3);
            int cp = clamp511(x+1) - (tx0-3);
            float a00 = sBlur[r0][cm], a01 = sBlur[r0][cc], a02 = sBlur[r0][cp];
            float a10 = sBlur[r1][cm],                      a12 = sBlur[r1][cp];
            float a20 = sBlur[r2][cm], a21 = sBlur[r2][cc], a22 = sBlur[r2][cp];
            float gxv = ((a02 + 2.f*a12 + a22) - (a00 + 2.f*a10 + a20)) * 0.125f;
            float gyv = ((a20 + 2.f*a21 + a22) - (a00 + 2.f*a01 + a02)) * 0.125f;
            m = sqrtf(gxv*gxv + gyv*gyv + 1e-6f);
            float agx = fabsf(gxv), agy = fabsf(gyv);
            if      (agy <= 0.41421356f * agx) k = (gxv >= 0.f) ? 0 : 4;
            else if (agy >= 2.41421356f * agx) k = (gyv >  0.f) ? 2 : 6;
            else k = (gyv > 0.f) ? ((gxv > 0.f) ? 1 : 3) : ((gxv > 0.f) ? 7 : 5);
        }
        uT.mag[r][c] = m;
        sDir[r][c] = (uint8_t)k;
    }
    __syncthreads();

    // ---- D: NMS + double threshold -> class [34][66] (overwrites gray) ----
    for (int u = tid; u < EY*EX; u += 256) {
        int r = u / EX, c = u - r*EX;
        float m = uT.mag[r+1][c+1];
        int p  = sDir[r+1][c+1];
        int qd = (p + 4) & 7;
        int dy1 = (int)((DYP >> (p*4))  & 7u) - 1;
        int dx1 = (int)((DXP >> (p*4))  & 7u) - 1;
        int dy2 = (int)((DYP >> (qd*4)) & 7u) - 1;
        int dx2 = (int)((DXP >> (qd*4)) & 7u) - 1;
        float n1 = uT.mag[r+1+dy1][c+1+dx1];
        float n2 = uT.mag[r+1+dy2][c+1+dx2];
        float mm = (fminf(m - n1, m - n2) > 0.f) ? m : 0.f;
        uA.e[r][c] = (mm > 0.1f) + (mm > 0.2f);
    }
    __syncthreads();

    // ---- E: guarded 1-sweep hysteresis + MSE, 2 quads/thread ----
    {
        float lacc = 0.f;
        #pragma unroll
        for (int half = 0; half < 2; ++half) {
            int uq = tid + half*256;          // quad id in [0,512)
            int r  = uq >> 4, q16 = uq & 15;
            int gy = ty0 + r, gx = tx0 + q16*4;
            int er = r + 1;
            int ec = q16*4 + 1;
            int cls[4];
            #pragma unroll
            for (int j = 0; j < 4; ++j) cls[j] = uA.e[er][ec+j];
            if (cls[0] == 1 || cls[1] == 1 || cls[2] == 1 || cls[3] == 1) {
                #pragma unroll
                for (int j = 0; j < 4; ++j) {
                    if (cls[j] == 1) {
                        int cc = ec + j;
                        bool pr = (uA.e[er-1][cc-1] == 2) | (uA.e[er-1][cc] == 2) | (uA.e[er-1][cc+1] == 2)
                                | (uA.e[er  ][cc-1] == 2) |                         (uA.e[er  ][cc+1] == 2)
                                | (uA.e[er+1][cc-1] == 2) | (uA.e[er+1][cc] == 2) | (uA.e[er+1][cc+1] == 2);
                        if (pr) cls[j] = 2;
                    }
                }
            }
            float4 s4 = *(const float4*)(sb + gy*W_ + gx);
            float4 m4 = *(const float4*)(mb + gy*W_ + gx);
            float tt, d;
            tt = fminf(fmaxf(s4.x*m4.x, 0.f), 1.f); d = 0.5f*(float)cls[0] - tt; lacc += d*d;
            tt = fminf(fmaxf(s4.y*m4.y, 0.f), 1.f); d = 0.5f*(float)cls[1] - tt; lacc += d*d;
            tt = fminf(fmaxf(s4.z*m4.z, 0.f), 1.f); d = 0.5f*(float)cls[2] - tt; lacc += d*d;
            tt = fminf(fmaxf(s4.w*m4.w, 0.f), 1.f); d = 0.5f*(float)cls[3] - tt; lacc += d*d;
        }
        #pragma unroll
        for (int off = 32; off > 0; off >>= 1)
            lacc += __shfl_down(lacc, off, 64);
        if ((tid & 63) == 0) wsum[tid >> 6] = lacc;
    }
    __syncthreads();
    if (tid == 0) {
        int bid = (blockIdx.z * gridDim.y + blockIdx.y) * gridDim.x + blockIdx.x;
        partials[bid] = wsum[0] + wsum[1] + wsum[2] + wsum[3];
    }
}

__global__ __launch_bounds__(256)
void k_final(const float* __restrict__ partials, float* __restrict__ out) {
    int tid = threadIdx.x;
    float acc = 0.f;
    #pragma unroll
    for (int j = 0; j < NBLK/256; ++j) acc += partials[j*256 + tid];
    #pragma unroll
    for (int off = 32; off > 0; off >>= 1)
        acc += __shfl_down(acc, off, 64);
    __shared__ float ws[4];
    if ((tid & 63) == 0) ws[tid >> 6] = acc;
    __syncthreads();
    if (tid == 0) out[0] = (ws[0] + ws[1] + ws[2] + ws[3]) * (1.0f / (float)N_);
}

extern "C" void kernel_launch(void* const* d_in, const int* in_sizes, int n_in,
                              void* d_out, int out_size, void* d_ws, size_t ws_size,
                              hipStream_t stream) {
    const float* pred   = (const float*)d_in[0];
    const float* sketch = (const float*)d_in[1];
    const float* matte  = (const float*)d_in[2];
    float* out = (float*)d_out;
    float* partials = (float*)d_ws;   // NBLK floats

    dim3 blk(256);
    dim3 grd(W_/TX, H_/TY, B_);   // (8, 16, 16) = 2048 blocks
    k_canny<<<grd, blk, 0, stream>>>(pred, sketch, matte, partials);
    k_final<<<1, blk, 0, stream>>>(partials, out);
}

// Round 6
// 47.683 us; speedup vs baseline: 1.6061x; 1.0490x over previous
//
#include <hip/hip_runtime.h>
#include <stdint.h>

#define B_  16
#define H_  512
#define W_  512
#define HW_ (H_*W_)
#define N_  (B_*HW_)

#define TX 64
#define TY 32
#define NBLK 2048

// plane geometry (flat-indexed)
#define GYr 42
#define GXc 80     // gray: rows ty0-5.., cols tx0-8..
#define TWYr 42
#define TWXc 70    // t: rows ty0-5.., cols tx0-3..
#define BLYr 38
#define BLXc 70    // blur: rows ty0-3.., cols tx0-3..
#define MGYr 36
#define MGXc 68    // mag/soff: rows ty0-2.., cols tx0-2..
#define EYr 34
#define EXc 66     // e: rows ty0-1.., cols tx0-1..

#define G0 0.054488685f
#define G1 0.244201342f
#define G2 0.402619947f

__device__ __forceinline__ int reflect512(int i) {
    i = i < 0 ? -i : i;
    return i > 511 ? 1022 - i : i;
}
__device__ __forceinline__ int clamp511(int v) {
    return v < 0 ? 0 : (v > 511 ? 511 : v);
}

__global__ __launch_bounds__(256)
void k_canny(const float* __restrict__ pred, const float* __restrict__ sketch,
             const float* __restrict__ matte, float* __restrict__ partials) {
    // g (13440B) / blur (10640B) / e (8976B) are pairwise non-overlapping in time
    __shared__ __align__(16) union {
        float g[GYr*GXc];
        float blur[BLYr*BLXc];
        int   e[EYr*EXc];
    } uA;
    // t (11760B) / mag (9792B)
    __shared__ __align__(16) union {
        float t[TWYr*TWXc];
        float mag[MGYr*MGXc];
    } uT;
    __shared__ int16_t sOff[MGYr*MGXc];
    __shared__ float wsum[4];

    const int tid = threadIdx.x;
    const int tx0 = blockIdx.x * TX;
    const int ty0 = blockIdx.y * TY;
    const int b   = blockIdx.z;
    const bool interior = (blockIdx.x >= 1) & (blockIdx.x <= 6) &
                          (blockIdx.y >= 1) & (blockIdx.y <= 14);

    const float* pb = pred   + (size_t)b * 3 * HW_;
    const float* mb = matte  + (size_t)b * HW_;
    const float* sb = sketch + (size_t)b * HW_;

    // ---- A: gray = mean3(pred)*matte, reflect-staged, 42x80, float4 quads ----
    {
        const bool xfast = (tx0 >= 8) && (tx0 + 71 < W_);
        for (int u = tid; u < GYr*20; u += 256) {
            int r = u / 20, q = u - r*20;
            int ys = reflect512(ty0 - 5 + r);
            int gx = tx0 - 8 + q*4;
            float4 res;
            if (xfast) {
                const float* prow = pb + ys*W_ + gx;
                float4 p0 = *(const float4*)(prow);
                float4 p1 = *(const float4*)(prow + HW_);
                float4 p2 = *(const float4*)(prow + 2*HW_);
                float4 m4 = *(const float4*)(mb + ys*W_ + gx);
                res.x = (p0.x+p1.x+p2.x)*m4.x*(1.f/3.f);
                res.y = (p0.y+p1.y+p2.y)*m4.y*(1.f/3.f);
                res.z = (p0.z+p1.z+p2.z)*m4.z*(1.f/3.f);
                res.w = (p0.w+p1.w+p2.w)*m4.w*(1.f/3.f);
            } else {
                float tmp[4];
                #pragma unroll
                for (int e2 = 0; e2 < 4; ++e2) {
                    int xs = reflect512(gx + e2);
                    int o  = ys*W_ + xs;
                    tmp[e2] = (pb[o] + pb[o+HW_] + pb[o+2*HW_]) * mb[o] * (1.f/3.f);
                }
                res.x = tmp[0]; res.y = tmp[1]; res.z = tmp[2]; res.w = tmp[3];
            }
            *(float4*)&uA.g[4*u] = res;   // r*80 + q*4 == 4u
        }
    }
    __syncthreads();

    // ---- B1: horizontal gaussian -> t [42][70] ----
    {
        int r = tid / TWXc, c = tid - (tid / TWXc) * TWXc;
        if (interior) {
            #pragma unroll
            for (int it = 0; it < 12; ++it) {
                if (r < TWYr) {
                    int gi = r*GXc + c + 3;      // g col (c+5) - 2
                    uT.t[r*TWXc + c] =
                        G0*uA.g[gi] + G1*uA.g[gi+1] + G2*uA.g[gi+2]
                      + G1*uA.g[gi+3] + G0*uA.g[gi+4];
                }
                c += 46; r += 3; if (c >= TWXc) { c -= TWXc; ++r; }
            }
        } else {
            #pragma unroll
            for (int it = 0; it < 12; ++it) {
                if (r < TWYr) {
                    int xc = clamp511(tx0 - 3 + c) - (tx0 - 8);
                    int gi = r*GXc + xc;
                    uT.t[r*TWXc + c] =
                        G0*uA.g[gi-2] + G1*uA.g[gi-1] + G2*uA.g[gi]
                      + G1*uA.g[gi+1] + G0*uA.g[gi+2];
                }
                c += 46; r += 3; if (c >= TWXc) { c -= TWXc; ++r; }
            }
        }
    }
    __syncthreads();

    // ---- B2: vertical gaussian -> blur [38][70] (aliases g) ----
    {
        int r = tid / BLXc, c = tid - (tid / BLXc) * BLXc;
        if (interior) {
            #pragma unroll
            for (int it = 0; it < 11; ++it) {
                if (r < BLYr) {
                    int ti = r*TWXc + c;         // t row (r+2) - 2
                    uA.blur[r*BLXc + c] =
                        G0*uT.t[ti] + G1*uT.t[ti+70] + G2*uT.t[ti+140]
                      + G1*uT.t[ti+210] + G0*uT.t[ti+280];
                }
                c += 46; r += 3; if (c >= BLXc) { c -= BLXc; ++r; }
            }
        } else {
            #pragma unroll
            for (int it = 0; it < 11; ++it) {
                if (r < BLYr) {
                    int yc = clamp511(ty0 - 3 + r) - (ty0 - 5);   // [2,39]
                    int ti = (yc-2)*TWXc + c;
                    uA.blur[r*BLXc + c] =
                        G0*uT.t[ti] + G1*uT.t[ti+70] + G2*uT.t[ti+140]
                      + G1*uT.t[ti+210] + G0*uT.t[ti+280];
                }
                c += 46; r += 3; if (c >= BLXc) { c -= BLXc; ++r; }
            }
        }
    }
    __syncthreads();

    // ---- C: sobel -> mag2 [36][68] (aliases t) + NMS offset ----
    {
        int r = tid / MGXc, c = tid - (tid / MGXc) * MGXc;
        if (interior) {
            #pragma unroll
            for (int it = 0; it < 10; ++it) {
                if (r < MGYr) {
                    int bi = r*BLXc + c;
                    float a00 = uA.blur[bi],     a01 = uA.blur[bi+1],   a02 = uA.blur[bi+2];
                    float a10 = uA.blur[bi+70],                         a12 = uA.blur[bi+72];
                    float a20 = uA.blur[bi+140], a21 = uA.blur[bi+141], a22 = uA.blur[bi+142];
                    float gxv = (a02 + 2.f*a12 + a22) - (a00 + 2.f*a10 + a20);
                    float gyv = (a20 + 2.f*a21 + a22) - (a00 + 2.f*a01 + a02);
                    float m2  = fmaf(gxv*gxv + gyv*gyv, 0.015625f, 1e-6f);
                    float agx = fabsf(gxv), agy = fabsf(gyv);
                    int off;
                    if      (agy <= 0.41421356f * agx) off = (gxv >= 0.f) ? 1 : -1;
                    else if (agy >= 2.41421356f * agx) off = (gyv >  0.f) ? -MGXc : MGXc;
                    else off = ((gyv > 0.f) ? -MGXc : MGXc) + ((gxv > 0.f) ? 1 : -1);
                    int mi = r*MGXc + c;
                    uT.mag[mi] = m2;
                    sOff[mi] = (int16_t)off;
                }
                c += 52; r += 3; if (c >= MGXc) { c -= MGXc; ++r; }
            }
        } else {
            #pragma unroll
            for (int it = 0; it < 10; ++it) {
                if (r < MGYr) {
                    int y = ty0 - 2 + r, x = tx0 - 2 + c;
                    float m2 = 0.f; int off = 0;
                    if ((unsigned)y < 512u && (unsigned)x < 512u) {
                        int r0 = clamp511(y-1) - (ty0-3);
                        int r1 = y - (ty0-3);
                        int r2 = clamp511(y+1) - (ty0-3);
                        int cm = clamp511(x-1) - (tx0-3);
                        int cc = x - (tx0-3);
                        int cp = clamp511(x+1) - (tx0-3);
                        float a00 = uA.blur[r0*BLXc+cm], a01 = uA.blur[r0*BLXc+cc], a02 = uA.blur[r0*BLXc+cp];
                        float a10 = uA.blur[r1*BLXc+cm],                            a12 = uA.blur[r1*BLXc+cp];
                        float a20 = uA.blur[r2*BLXc+cm], a21 = uA.blur[r2*BLXc+cc], a22 = uA.blur[r2*BLXc+cp];
                        float gxv = (a02 + 2.f*a12 + a22) - (a00 + 2.f*a10 + a20);
                        float gyv = (a20 + 2.f*a21 + a22) - (a00 + 2.f*a01 + a02);
                        m2 = fmaf(gxv*gxv + gyv*gyv, 0.015625f, 1e-6f);
                        float agx = fabsf(gxv), agy = fabsf(gyv);
                        if      (agy <= 0.41421356f * agx) off = (gxv >= 0.f) ? 1 : -1;
                        else if (agy >= 2.41421356f * agx) off = (gyv >  0.f) ? -MGXc : MGXc;
                        else off = ((gyv > 0.f) ? -MGXc : MGXc) + ((gxv > 0.f) ? 1 : -1);
                    }
                    int mi = r*MGXc + c;
                    uT.mag[mi] = m2;
                    sOff[mi] = (int16_t)off;
                }
                c += 52; r += 3; if (c >= MGXc) { c -= MGXc; ++r; }
            }
        }
    }
    __syncthreads();

    // ---- D: NMS + double threshold -> class [34][66] (aliases blur) ----
    {
        int r = tid / EXc, c = tid - (tid / EXc) * EXc;
        #pragma unroll
        for (int it = 0; it < 9; ++it) {
            if (r < EYr) {
                int mi = r*MGXc + c + MGXc + 1;     // center
                float m2 = uT.mag[mi];
                int off = (int)sOff[mi];
                float n1 = uT.mag[mi + off];
                float n2 = uT.mag[mi - off];
                int cls = 0;
                if (m2 > n1 && m2 > n2) cls = (m2 > 0.01f) + (m2 > 0.04f);
                uA.e[r*EXc + c] = cls;
            }
            c += 58; r += 3; if (c >= EXc) { c -= EXc; ++r; }
        }
    }
    __syncthreads();

    // ---- E: guarded 1-sweep hysteresis + MSE, 2 quads/thread ----
    {
        float lacc = 0.f;
        #pragma unroll
        for (int half = 0; half < 2; ++half) {
            int uq = tid + half*256;          // quad id in [0,512)
            int r  = uq >> 4, q16 = uq & 15;
            int gy = ty0 + r, gx = tx0 + q16*4;
            int ei = (r+1)*EXc + q16*4 + 1;
            int cls[4];
            #pragma unroll
            for (int j = 0; j < 4; ++j) cls[j] = uA.e[ei+j];
            if (cls[0] == 1 || cls[1] == 1 || cls[2] == 1 || cls[3] == 1) {
                #pragma unroll
                for (int j = 0; j < 4; ++j) {
                    if (cls[j] == 1) {
                        int cc = ei + j;
                        bool pr = (uA.e[cc-EXc-1] == 2) | (uA.e[cc-EXc] == 2) | (uA.e[cc-EXc+1] == 2)
                                | (uA.e[cc-1]     == 2) |                       (uA.e[cc+1]     == 2)
                                | (uA.e[cc+EXc-1] == 2) | (uA.e[cc+EXc] == 2) | (uA.e[cc+EXc+1] == 2);
                        if (pr) cls[j] = 2;
                    }
                }
            }
            float4 s4 = *(const float4*)(sb + gy*W_ + gx);
            float4 m4 = *(const float4*)(mb + gy*W_ + gx);
            float tt, d;
            tt = fminf(fmaxf(s4.x*m4.x, 0.f), 1.f); d = 0.5f*(float)cls[0] - tt; lacc += d*d;
            tt = fminf(fmaxf(s4.y*m4.y, 0.f), 1.f); d = 0.5f*(float)cls[1] - tt; lacc += d*d;
            tt = fminf(fmaxf(s4.z*m4.z, 0.f), 1.f); d = 0.5f*(float)cls[2] - tt; lacc += d*d;
            tt = fminf(fmaxf(s4.w*m4.w, 0.f), 1.f); d = 0.5f*(float)cls[3] - tt; lacc += d*d;
        }
        #pragma unroll
        for (int off = 32; off > 0; off >>= 1)
            lacc += __shfl_down(lacc, off, 64);
        if ((tid & 63) == 0) wsum[tid >> 6] = lacc;
    }
    __syncthreads();
    if (tid == 0) {
        int bid = (blockIdx.z * gridDim.y + blockIdx.y) * gridDim.x + blockIdx.x;
        partials[bid] = wsum[0] + wsum[1] + wsum[2] + wsum[3];
    }
}

__global__ __launch_bounds__(256)
void k_final(const float* __restrict__ partials, float* __restrict__ out) {
    int tid = threadIdx.x;
    float acc = 0.f;
    #pragma unroll
    for (int j = 0; j < NBLK/256; ++j) acc += partials[j*256 + tid];
    #pragma unroll
    for (int off = 32; off > 0; off >>= 1)
        acc += __shfl_down(acc, off, 64);
    __shared__ float ws[4];
    if ((tid & 63) == 0) ws[tid >> 6] = acc;
    __syncthreads();
    if (tid == 0) out[0] = (ws[0] + ws[1] + ws[2] + ws[3]) * (1.0f / (float)N_);
}

extern "C" void kernel_launch(void* const* d_in, const int* in_sizes, int n_in,
                              void* d_out, int out_size, void* d_ws, size_t ws_size,
                              hipStream_t stream) {
    const float* pred   = (const float*)d_in[0];
    const float* sketch = (const float*)d_in[1];
    const float* matte  = (const float*)d_in[2];
    float* out = (float*)d_out;
    float* partials = (float*)d_ws;   // NBLK floats

    dim3 blk(256);
    dim3 grd(W_/TX, H_/TY, B_);   // (8, 16, 16) = 2048 blocks
    k_canny<<<grd, blk, 0, stream>>>(pred, sketch, matte, partials);
    k_final<<<1, blk, 0, stream>>>(partials, out);
}